// Round 3
// baseline (459.706 us; speedup 1.0000x reference)
//
#include <hip/hip_runtime.h>
#include <hip/hip_bf16.h>
#include <cstdint>
#include <cstddef>

#define NN 8192
#define FIN 256
#define FOUT 64
#define ALPHA_SLOPE 0.2f
#define EXP_M10 4.5399929762484854e-05f   // exp(-10)

#define JSPLIT 16   // j-range splits (each wave covers 512 j's)
#define KITER 16    // (NN/JSPLIT)/32 inner iterations, fully unrolled
#define CP 68       // slab column pitch (64 feats + 1 denom + pad)

typedef short s16x8 __attribute__((ext_vector_type(8)));
typedef float f32x4 __attribute__((ext_vector_type(4)));
typedef int   i32x4 __attribute__((ext_vector_type(4)));
typedef float f32x4v __attribute__((ext_vector_type(4)));

__device__ __forceinline__ unsigned short f2bf(float x) {
    union { float f; uint32_t u; } v; v.f = x;
    uint32_t u = v.u;
    return (unsigned short)((u + 0x7FFFu + ((u >> 16) & 1u)) >> 16);  // RNE
}

// ---------------- Kernel 1: h = input@W, s1 = h@a1, s2 = h@a2, htg = bf16(h)^T ----
__global__ __launch_bounds__(256) void k_h(
    const float* __restrict__ input, const float* __restrict__ W,
    const float* __restrict__ a,
    unsigned short* __restrict__ htg, float* __restrict__ s1, float* __restrict__ s2)
{
    __shared__ __align__(16) unsigned short tile[64][28];  // [feat][row], pitch 28
    const int wid  = threadIdx.x >> 6;
    const int lane = threadIdx.x & 63;
    const int i0   = blockIdx.x * 16;
    const int r0   = wid * 4;
    const float* inb = input + (size_t)(i0 + r0) * FIN;

    float acc0 = 0.f, acc1 = 0.f, acc2 = 0.f, acc3 = 0.f;
    #pragma unroll 4
    for (int c = 0; c < FIN; c += 4) {
        float w0 = W[(c + 0) * FOUT + lane];
        float w1 = W[(c + 1) * FOUT + lane];
        float w2 = W[(c + 2) * FOUT + lane];
        float w3 = W[(c + 3) * FOUT + lane];
        float4 x0 = *(const float4*)(inb + 0 * FIN + c);
        float4 x1 = *(const float4*)(inb + 1 * FIN + c);
        float4 x2 = *(const float4*)(inb + 2 * FIN + c);
        float4 x3 = *(const float4*)(inb + 3 * FIN + c);
        acc0 = fmaf(x0.x, w0, fmaf(x0.y, w1, fmaf(x0.z, w2, fmaf(x0.w, w3, acc0))));
        acc1 = fmaf(x1.x, w0, fmaf(x1.y, w1, fmaf(x1.z, w2, fmaf(x1.w, w3, acc1))));
        acc2 = fmaf(x2.x, w0, fmaf(x2.y, w1, fmaf(x2.z, w2, fmaf(x2.w, w3, acc2))));
        acc3 = fmaf(x3.x, w0, fmaf(x3.y, w1, fmaf(x3.z, w2, fmaf(x3.w, w3, acc3))));
    }

    const float a1v = a[lane], a2v = a[FOUT + lane];
    float accs[4] = {acc0, acc1, acc2, acc3};
    #pragma unroll
    for (int r = 0; r < 4; ++r) {
        float v1 = accs[r] * a1v;
        float v2 = accs[r] * a2v;
        #pragma unroll
        for (int off = 32; off; off >>= 1) {
            v1 += __shfl_xor(v1, off);
            v2 += __shfl_xor(v2, off);
        }
        if (lane == 0) { s1[i0 + r0 + r] = v1; s2[i0 + r0 + r] = v2; }
        tile[lane][r0 + r] = f2bf(accs[r]);
    }
    __syncthreads();

    const int feat = threadIdx.x >> 2;
    const int cg   = (threadIdx.x & 3) * 4;
    uint2 q = *(const uint2*)&tile[feat][cg];
    *(uint2*)(htg + (size_t)feat * NN + i0 + cg) = q;
}

// ---------------- Kernel 2: fused mask/exp + (P @ [h | 1]) — register-direct -------
// Each wave: 16-row i-tile x 512-col j-range. Fully-unrolled K-loop: all streams
// advance via immediate offsets from fixed base pointers (zero addr VALU in loop),
// adj loads are non-temporal (touch-once stream, keep L1 for htg), and the
// unrolled body lets the scheduler keep many loads in flight (MLP).
__global__ __launch_bounds__(256, 4) void k_attn(
    const int* __restrict__ adj,
    const unsigned short* __restrict__ htg,
    const float* __restrict__ s1g, const float* __restrict__ s2g,
    float* __restrict__ slabs)
{
    const int t    = threadIdx.x;
    const int wid  = t >> 6;
    const int lane = t & 63;
    const int gw   = blockIdx.x * 4 + wid;   // global wave id, 0..8191
    const int mi   = gw >> 4;                // i-tile index (0..511)
    const int js   = gw & 15;                // j-split (0..15)
    const int m    = lane & 15;
    const int quad = lane >> 4;
    const int irow = mi * 16 + m;
    const int jb   = js * (NN / JSPLIT) + quad * 8;

    const float s1v = s1g[irow];

    const short bd = (m == 0) ? (short)0x3F80 : (short)0;  // bf16 1.0 or 0
    const s16x8 bden = {bd, bd, bd, bd, bd, bd, bd, bd};

    f32x4 acc0 = {0,0,0,0}, acc1 = {0,0,0,0}, acc2 = {0,0,0,0},
          acc3 = {0,0,0,0}, acc4 = {0,0,0,0};

    const int*   aptr = adj + (size_t)irow * NN + jb;
    const float* s2p  = s2g + jb;
    const unsigned short* h0 = htg + (size_t)(m +  0) * NN + jb;
    const unsigned short* h1 = htg + (size_t)(m + 16) * NN + jb;
    const unsigned short* h2 = htg + (size_t)(m + 32) * NN + jb;
    const unsigned short* h3 = htg + (size_t)(m + 48) * NN + jb;

    #pragma unroll
    for (int ko = 0; ko < KITER; ++ko) {
        const int o = ko * 32;
        i32x4  av0 = __builtin_nontemporal_load((const i32x4*)(aptr + o));
        i32x4  av1 = __builtin_nontemporal_load((const i32x4*)(aptr + o + 4));
        float4 sa  = *(const float4*)(s2p + o);
        float4 sb  = *(const float4*)(s2p + o + 4);
        s16x8  b0  = *(const s16x8*)(h0 + o);
        s16x8  b1  = *(const s16x8*)(h1 + o);
        s16x8  b2  = *(const s16x8*)(h2 + o);
        s16x8  b3  = *(const s16x8*)(h3 + o);

        float x0 = s1v + sa.x, x1 = s1v + sa.y, x2 = s1v + sa.z, x3 = s1v + sa.w;
        float x4 = s1v + sb.x, x5 = s1v + sb.y, x6 = s1v + sb.z, x7 = s1v + sb.w;
        float w0 = (av0.x > 0) ? __expf(fmaxf(x0, ALPHA_SLOPE * x0)) : EXP_M10;
        float w1 = (av0.y > 0) ? __expf(fmaxf(x1, ALPHA_SLOPE * x1)) : EXP_M10;
        float w2 = (av0.z > 0) ? __expf(fmaxf(x2, ALPHA_SLOPE * x2)) : EXP_M10;
        float w3 = (av0.w > 0) ? __expf(fmaxf(x3, ALPHA_SLOPE * x3)) : EXP_M10;
        float w4 = (av1.x > 0) ? __expf(fmaxf(x4, ALPHA_SLOPE * x4)) : EXP_M10;
        float w5 = (av1.y > 0) ? __expf(fmaxf(x5, ALPHA_SLOPE * x5)) : EXP_M10;
        float w6 = (av1.z > 0) ? __expf(fmaxf(x6, ALPHA_SLOPE * x6)) : EXP_M10;
        float w7 = (av1.w > 0) ? __expf(fmaxf(x7, ALPHA_SLOPE * x7)) : EXP_M10;

        s16x8 af;
        af[0] = (short)f2bf(w0); af[1] = (short)f2bf(w1);
        af[2] = (short)f2bf(w2); af[3] = (short)f2bf(w3);
        af[4] = (short)f2bf(w4); af[5] = (short)f2bf(w5);
        af[6] = (short)f2bf(w6); af[7] = (short)f2bf(w7);

        acc0 = __builtin_amdgcn_mfma_f32_16x16x32_bf16(af, b0,   acc0, 0, 0, 0);
        acc1 = __builtin_amdgcn_mfma_f32_16x16x32_bf16(af, b1,   acc1, 0, 0, 0);
        acc2 = __builtin_amdgcn_mfma_f32_16x16x32_bf16(af, b2,   acc2, 0, 0, 0);
        acc3 = __builtin_amdgcn_mfma_f32_16x16x32_bf16(af, b3,   acc3, 0, 0, 0);
        acc4 = __builtin_amdgcn_mfma_f32_16x16x32_bf16(af, bden, acc4, 0, 0, 0);
    }

    // epilogue: C row = quad*4 + reg (i), col = m (feature within 16-block)
    float* slab = slabs + (size_t)js * ((size_t)NN * CP);
    const int r0 = mi * 16 + quad * 4;
    #pragma unroll
    for (int reg = 0; reg < 4; ++reg) {
        size_t ro = (size_t)(r0 + reg) * CP;
        slab[ro +  0 + m] = acc0[reg];
        slab[ro + 16 + m] = acc1[reg];
        slab[ro + 32 + m] = acc2[reg];
        slab[ro + 48 + m] = acc3[reg];
        if (m == 0) slab[ro + 64] = acc4[reg];
    }
}

// ---------------- Kernel 3: reduce splits, normalize, ELU --------------------------
__global__ __launch_bounds__(256) void k_norm(
    const float* __restrict__ slabs, float* __restrict__ out)
{
    int gid = blockIdx.x * 256 + threadIdx.x;
    int i = gid >> 6, k = gid & 63;
    float num = 0.f, den = 0.f;
    #pragma unroll
    for (int js = 0; js < JSPLIT; ++js) {
        const float* row = slabs + (size_t)js * ((size_t)NN * CP) + (size_t)i * CP;
        num += row[k];
        den += row[64];
    }
    float v = num / den;
    out[gid] = (v > 0.f) ? v : (__expf(v) - 1.f);
}

// ---------------- launch -----------------------------------------------------------
extern "C" void kernel_launch(void* const* d_in, const int* in_sizes, int n_in,
                              void* d_out, int out_size, void* d_ws, size_t ws_size,
                              hipStream_t stream) {
    const float* input = (const float*)d_in[0];
    const int*   adj   = (const int*)d_in[1];
    const float* W     = (const float*)d_in[2];
    const float* a     = (const float*)d_in[3];
    float* out = (float*)d_out;

    char* ws = (char*)d_ws;
    float* slabs = (float*)ws;
    size_t off = (size_t)JSPLIT * NN * CP * sizeof(float);      // 35.7 MB
    unsigned short* htg = (unsigned short*)(ws + off);
    off += (size_t)FOUT * NN * sizeof(unsigned short);          // 1 MB
    float* s1 = (float*)(ws + off); off += NN * sizeof(float);
    float* s2 = (float*)(ws + off);

    k_h   <<<NN / 16, 256, 0, stream>>>(input, W, a, htg, s1, s2);
    k_attn<<<(NN / 16) * JSPLIT / 4, 256, 0, stream>>>(adj, htg, s1, s2, slabs);
    k_norm<<<NN * FOUT / 256, 256, 0, stream>>>(slabs, out);
}

// Round 4
// 443.647 us; speedup vs baseline: 1.0362x; 1.0362x over previous
//
#include <hip/hip_runtime.h>
#include <hip/hip_bf16.h>
#include <cstdint>
#include <cstddef>

#define NN 8192
#define FIN 256
#define FOUT 64
#define ALPHA_SLOPE 0.2f
#define EXP_M10 4.5399929762484854e-05f   // exp(-10)

#define JSPLIT 2    // j-range splits; each block sweeps 4096 cols
#define JT 1024     // j columns per LDS tile
#define NTILE ((NN / JSPLIT) / JT)   // 4 tiles per block
#define CP 68       // slab column pitch (64 feats + 1 denom + pad)

typedef short s16x8 __attribute__((ext_vector_type(8)));
typedef float f32x4 __attribute__((ext_vector_type(4)));
typedef int   i32x4 __attribute__((ext_vector_type(4)));

__device__ __forceinline__ unsigned short f2bf(float x) {
    union { float f; uint32_t u; } v; v.f = x;
    uint32_t u = v.u;
    return (unsigned short)((u + 0x7FFFu + ((u >> 16) & 1u)) >> 16);  // RNE
}

// XOR-swizzled Wt layout: row pitch 1024 shorts (2 KB), 16B-chunk index XOR'd
// with (row&7). Keeps 16B alignment for ds_read_b128 AND spreads the 16 row
// streams across banks (pad-free; padded pitches give 8-way b128 conflicts).
__device__ __forceinline__ int wt_off(int row, int chunk) {
    return row * JT + (((chunk) ^ (row & 7)) << 3);   // short offset
}

// ---------------- Kernel 1: h = input@W, s1 = h@a1, s2 = h@a2, htg = bf16(h)^T ----
__global__ __launch_bounds__(256) void k_h(
    const float* __restrict__ input, const float* __restrict__ W,
    const float* __restrict__ a,
    unsigned short* __restrict__ htg, float* __restrict__ s1, float* __restrict__ s2)
{
    __shared__ __align__(16) unsigned short tile[64][28];
    const int wid  = threadIdx.x >> 6;
    const int lane = threadIdx.x & 63;
    const int i0   = blockIdx.x * 16;
    const int r0   = wid * 4;
    const float* inb = input + (size_t)(i0 + r0) * FIN;

    float acc0 = 0.f, acc1 = 0.f, acc2 = 0.f, acc3 = 0.f;
    #pragma unroll 4
    for (int c = 0; c < FIN; c += 4) {
        float w0 = W[(c + 0) * FOUT + lane];
        float w1 = W[(c + 1) * FOUT + lane];
        float w2 = W[(c + 2) * FOUT + lane];
        float w3 = W[(c + 3) * FOUT + lane];
        float4 x0 = *(const float4*)(inb + 0 * FIN + c);
        float4 x1 = *(const float4*)(inb + 1 * FIN + c);
        float4 x2 = *(const float4*)(inb + 2 * FIN + c);
        float4 x3 = *(const float4*)(inb + 3 * FIN + c);
        acc0 = fmaf(x0.x, w0, fmaf(x0.y, w1, fmaf(x0.z, w2, fmaf(x0.w, w3, acc0))));
        acc1 = fmaf(x1.x, w0, fmaf(x1.y, w1, fmaf(x1.z, w2, fmaf(x1.w, w3, acc1))));
        acc2 = fmaf(x2.x, w0, fmaf(x2.y, w1, fmaf(x2.z, w2, fmaf(x2.w, w3, acc2))));
        acc3 = fmaf(x3.x, w0, fmaf(x3.y, w1, fmaf(x3.z, w2, fmaf(x3.w, w3, acc3))));
    }

    const float a1v = a[lane], a2v = a[FOUT + lane];
    float accs[4] = {acc0, acc1, acc2, acc3};
    #pragma unroll
    for (int r = 0; r < 4; ++r) {
        float v1 = accs[r] * a1v;
        float v2 = accs[r] * a2v;
        #pragma unroll
        for (int off = 32; off; off >>= 1) {
            v1 += __shfl_xor(v1, off);
            v2 += __shfl_xor(v2, off);
        }
        if (lane == 0) { s1[i0 + r0 + r] = v1; s2[i0 + r0 + r] = v2; }
        tile[lane][r0 + r] = f2bf(accs[r]);
    }
    __syncthreads();

    const int feat = threadIdx.x >> 2;
    const int cg   = (threadIdx.x & 3) * 4;
    uint2 q = *(const uint2*)&tile[feat][cg];
    *(uint2*)(htg + (size_t)feat * NN + i0 + cg) = q;
}

// ---------------- Kernel 2: staged, DRAM-sequential fused attention ----------------
// Block: 16-row i-tile x 4096-col j-range (4 waves). Per 1024-col tile:
//   stage: wave w streams rows w*4..w*4+3 as 4KB sequential bursts, computes
//          w=exp(masked lrelu) in-register, stores bf16 to swizzled LDS.
//   mfma : wave w takes ko quarter [w*256, w*256+256), A from LDS, B direct
//          from L2-resident htg; 5th MFMA (B=[1,0..]) accumulates denominator.
// Block-level partial-acc reduction through LDS, one store per block to slab.
__global__ __launch_bounds__(256, 4) void k_attn(
    const int* __restrict__ adj,
    const unsigned short* __restrict__ htg,
    const float* __restrict__ s1g, const float* __restrict__ s2g,
    float* __restrict__ slabs)
{
    __shared__ __align__(16) unsigned short Wt[16 * JT];   // 32 KB, swizzled

    const int t    = threadIdx.x;
    const int wid  = t >> 6;
    const int lane = t & 63;
    const int bi   = blockIdx.x >> 1;       // i-tile (0..511)
    const int js   = blockIdx.x & 1;        // j-split (0..1)
    const int i0   = bi * 16;
    const int jbase = js * (NN / JSPLIT);
    const int m    = lane & 15;
    const int quad = lane >> 4;

    // staging rows for this wave
    const int srow = wid * 4;
    float s1r[4];
    #pragma unroll
    for (int r = 0; r < 4; ++r) s1r[r] = s1g[i0 + srow + r];

    const int kq = wid * (JT / 4);          // this wave's ko-quarter base col

    const short bd = (m == 0) ? (short)0x3F80 : (short)0;  // bf16 1.0 / 0
    const s16x8 bden = {bd, bd, bd, bd, bd, bd, bd, bd};

    f32x4 acc0 = {0,0,0,0}, acc1 = {0,0,0,0}, acc2 = {0,0,0,0},
          acc3 = {0,0,0,0}, acc4 = {0,0,0,0};

    for (int tile = 0; tile < NTILE; ++tile) {
        const int j0 = jbase + tile * JT;
        __syncthreads();   // previous tile's readers done before overwrite

        // ---- stage: 4 rows x 1024 cols, 4KB sequential per row ----
        #pragma unroll
        for (int rr = 0; rr < 4; ++rr) {
            const int row = srow + rr;
            const int* ap = adj + (size_t)(i0 + row) * NN + j0;
            const float s1v = s1r[rr];
            #pragma unroll
            for (int c = 0; c < 4; ++c) {
                const int cc = c * 256 + lane * 4;
                i32x4  av = *(const i32x4*)(ap + cc);
                float4 sv = *(const float4*)(s2g + j0 + cc);
                float x0 = s1v + sv.x, x1 = s1v + sv.y;
                float x2 = s1v + sv.z, x3 = s1v + sv.w;
                float w0 = (av.x > 0) ? __expf(fmaxf(x0, ALPHA_SLOPE * x0)) : EXP_M10;
                float w1 = (av.y > 0) ? __expf(fmaxf(x1, ALPHA_SLOPE * x1)) : EXP_M10;
                float w2 = (av.z > 0) ? __expf(fmaxf(x2, ALPHA_SLOPE * x2)) : EXP_M10;
                float w3 = (av.w > 0) ? __expf(fmaxf(x3, ALPHA_SLOPE * x3)) : EXP_M10;
                uint2 pk;
                pk.x = (unsigned int)f2bf(w0) | ((unsigned int)f2bf(w1) << 16);
                pk.y = (unsigned int)f2bf(w2) | ((unsigned int)f2bf(w3) << 16);
                const int chunk = c * 32 + (lane >> 1);
                *(uint2*)&Wt[wt_off(row, chunk) + (lane & 1) * 4] = pk;
            }
        }
        __syncthreads();

        // ---- mfma: this wave's ko-quarter ----
        #pragma unroll
        for (int ks = 0; ks < 8; ++ks) {
            const int kc = kq + ks * 32;
            s16x8 af = *(const s16x8*)&Wt[wt_off(m, (kc >> 3) + quad)];
            const unsigned short* hp = htg + (size_t)m * NN + j0 + kc + quad * 8;
            s16x8 b0 = *(const s16x8*)(hp);
            s16x8 b1 = *(const s16x8*)(hp + (size_t)16 * NN);
            s16x8 b2 = *(const s16x8*)(hp + (size_t)32 * NN);
            s16x8 b3 = *(const s16x8*)(hp + (size_t)48 * NN);
            acc0 = __builtin_amdgcn_mfma_f32_16x16x32_bf16(af, b0,   acc0, 0, 0, 0);
            acc1 = __builtin_amdgcn_mfma_f32_16x16x32_bf16(af, b1,   acc1, 0, 0, 0);
            acc2 = __builtin_amdgcn_mfma_f32_16x16x32_bf16(af, b2,   acc2, 0, 0, 0);
            acc3 = __builtin_amdgcn_mfma_f32_16x16x32_bf16(af, b3,   acc3, 0, 0, 0);
            acc4 = __builtin_amdgcn_mfma_f32_16x16x32_bf16(af, bden, acc4, 0, 0, 0);
        }
    }

    // ---- block reduction of the 4 waves' ko-partial accumulators ----
    __syncthreads();                 // all waves done reading Wt
    float* red = (float*)Wt;         // 4 x 16 x 68 floats = 17.4 KB <= 32 KB
    float* myred = red + wid * 16 * CP;
    #pragma unroll
    for (int reg = 0; reg < 4; ++reg) {
        const int r = quad * 4 + reg;
        myred[r * CP +  0 + m] = acc0[reg];
        myred[r * CP + 16 + m] = acc1[reg];
        myred[r * CP + 32 + m] = acc2[reg];
        myred[r * CP + 48 + m] = acc3[reg];
        if (m == 0) myred[r * CP + 64] = acc4[reg];
    }
    __syncthreads();

    float* slab = slabs + (size_t)js * ((size_t)NN * CP);
    for (int idx = t; idx < 16 * 65; idx += 256) {
        const int r = idx / 65, c = idx % 65;
        float s = red[0 * 16 * CP + r * CP + c] + red[1 * 16 * CP + r * CP + c]
                + red[2 * 16 * CP + r * CP + c] + red[3 * 16 * CP + r * CP + c];
        slab[(size_t)(i0 + r) * CP + c] = s;
    }
}

// ---------------- Kernel 3: reduce splits, normalize, ELU --------------------------
__global__ __launch_bounds__(256) void k_norm(
    const float* __restrict__ slabs, float* __restrict__ out)
{
    int gid = blockIdx.x * 256 + threadIdx.x;
    int i = gid >> 6, k = gid & 63;
    float num = 0.f, den = 0.f;
    #pragma unroll
    for (int js = 0; js < JSPLIT; ++js) {
        const float* row = slabs + (size_t)js * ((size_t)NN * CP) + (size_t)i * CP;
        num += row[k];
        den += row[64];
    }
    float v = num / den;
    out[gid] = (v > 0.f) ? v : (__expf(v) - 1.f);
}

// ---------------- launch -----------------------------------------------------------
extern "C" void kernel_launch(void* const* d_in, const int* in_sizes, int n_in,
                              void* d_out, int out_size, void* d_ws, size_t ws_size,
                              hipStream_t stream) {
    const float* input = (const float*)d_in[0];
    const int*   adj   = (const int*)d_in[1];
    const float* W     = (const float*)d_in[2];
    const float* a     = (const float*)d_in[3];
    float* out = (float*)d_out;

    char* ws = (char*)d_ws;
    float* slabs = (float*)ws;
    size_t off = (size_t)JSPLIT * NN * CP * sizeof(float);      // 4.5 MB
    unsigned short* htg = (unsigned short*)(ws + off);
    off += (size_t)FOUT * NN * sizeof(unsigned short);          // 1 MB
    float* s1 = (float*)(ws + off); off += NN * sizeof(float);
    float* s2 = (float*)(ws + off);

    k_h   <<<NN / 16, 256, 0, stream>>>(input, W, a, htg, s1, s2);
    k_attn<<<(NN / 16) * JSPLIT, 256, 0, stream>>>(adj, htg, s1, s2, slabs);
    k_norm<<<NN * FOUT / 256, 256, 0, stream>>>(slabs, out);
}